// Round 14
// baseline (158.942 us; speedup 1.0000x reference)
//
#include <hip/hip_runtime.h>

typedef __attribute__((ext_vector_type(8))) short bf16x8;
typedef __attribute__((ext_vector_type(4))) float f32x4;

#define C_DIM 256
#define K_CODES 1024
#define HW 1024
#define N_TOK 32768
#define OUT0_ELEMS 8388608
#define NSLOT 64
#define MARGIN_P (16777u * 1024u)   // 2e-3 * 2^23, in packed units

static __device__ __forceinline__ unsigned short f2bf(float f) {
    unsigned u = __float_as_uint(f);
    unsigned r = (u + 0x7FFFu + ((u >> 16) & 1u)) >> 16;
    return (unsigned short)r;
}
static __device__ __forceinline__ unsigned umin2(unsigned a, unsigned b) { return a < b ? a : b; }

// ---------------------------------------------------------------------------
// cb -> bf16 copy [K][C] + Bk (per-code |w|^2, numpy-pairwise f32, arithmetic
// bit-identical to the original bk_kernel, run by lane 0 of each block).
// ---------------------------------------------------------------------------
__global__ __launch_bounds__(64) void cbh_bk_kernel(const float* __restrict__ cb,
        unsigned short* __restrict__ cb_h, float* __restrict__ Bk) {
#pragma clang fp contract(off)
    int k = blockIdx.x, l = threadIdx.x;
    const float4 v = *(const float4*)&cb[k * C_DIM + l * 4];
    ushort4 o;
    o.x = f2bf(v.x); o.y = f2bf(v.y); o.z = f2bf(v.z); o.w = f2bf(v.w);
    *(ushort4*)&cb_h[k * C_DIM + l * 4] = o;
    if (l == 0) {
        const float* w = cb + k * C_DIM;
        float s[2];
        for (int h = 0; h < 2; ++h) {
            const float* p = w + h * 128;
            float r[8];
            #pragma unroll
            for (int j = 0; j < 8; ++j) { float vv = p[j]; r[j] = vv * vv; }
            for (int i = 8; i < 128; i += 8) {
                #pragma unroll
                for (int j = 0; j < 8; ++j) { float vv = p[i + j]; r[j] = r[j] + vv * vv; }
            }
            s[h] = ((r[0] + r[1]) + (r[2] + r[3])) + ((r[4] + r[5]) + (r[6] + r[7]));
        }
        Bk[k] = s[0] + s[1];
    }
}

// ---------------------------------------------------------------------------
// z prep: NCHW f32 -> z_t f32 [N][C] (in d_out region, overwritten later by
// out_kernel), z_h bf16 [N][C], A[N] = |z|^2 numpy-pairwise.
// ---------------------------------------------------------------------------
__global__ __launch_bounds__(256) void zprep_kernel(const float* __restrict__ z,
        float* __restrict__ z_t, unsigned short* __restrict__ z_h,
        float* __restrict__ A) {
#pragma clang fp contract(off)
    __shared__ float tile[64 * 257];
    const int t = threadIdx.x, blk = blockIdx.x;
    const int b = blk >> 4, hw0 = (blk & 15) * 64, tok0 = blk * 64;
    const size_t zb = (size_t)b * (C_DIM * HW) + hw0;
    for (int i = 0; i < 64; ++i) {
        int pos = i * 256 + t;
        int c = pos >> 6, hw = pos & 63;
        tile[hw * 257 + c] = z[zb + (size_t)c * HW + hw];
    }
    __syncthreads();
    if (t < 64) {
        const float* p0 = &tile[t * 257];
        float s[2];
        for (int h = 0; h < 2; ++h) {
            const float* p = p0 + h * 128;
            float r[8];
            #pragma unroll
            for (int j = 0; j < 8; ++j) { float v = p[j]; r[j] = v * v; }
            for (int i = 8; i < 128; i += 8) {
                #pragma unroll
                for (int j = 0; j < 8; ++j) { float v = p[i + j]; r[j] = r[j] + v * v; }
            }
            s[h] = ((r[0] + r[1]) + (r[2] + r[3])) + ((r[4] + r[5]) + (r[6] + r[7]));
        }
        A[tok0 + t] = s[0] + s[1];
    }
    for (int i = 0; i < 64; ++i) {
        int pos = i * 256 + t;
        int tl = pos >> 8, c = pos & 255;
        float v = tile[tl * 257 + c];
        z_t[(size_t)(tok0 + tl) * 256 + c] = v;
        z_h[(size_t)(tok0 + tl) * 256 + c] = f2bf(v);
    }
}

// ---------------------------------------------------------------------------
// Main: R13's proven structure + T14 async-STAGE split: chunk kc+1 is
// prefetched into registers while chunk kc's MFMAs run; the ds_write lands
// after the next barrier. Inner MFMA/tail codegen unchanged from R13.
// ---------------------------------------------------------------------------
__global__ __launch_bounds__(256, 2) void vq_main(
        const unsigned short* __restrict__ z_h, const unsigned short* __restrict__ cb_h,
        const float* __restrict__ A, const float* __restrict__ Bk,
        const float* __restrict__ z_t, const float* __restrict__ cb,
        float* __restrict__ out_idx) {
#pragma clang fp contract(off)
    __shared__ __align__(16) char zs[32768];
    __shared__ __align__(16) char wsm[32768];
    __shared__ unsigned gpart[64][4];
    __shared__ int cnt[64];
    __shared__ unsigned short ck[64 * NSLOT];
    __shared__ float bval[64][4];
    __shared__ int   bidx[64][4];

    const int tid = threadIdx.x;
    const int w = tid >> 6, l = tid & 63;
    const int lq = l >> 4, lr = l & 15;
    const int tok0 = blockIdx.x * 64;

    // per-thread staging geometry (kc-invariant)
    int s_code[8], s_c8[8];
    #pragma unroll
    for (int i = 0; i < 8; ++i) {
        int unit = i * 256 + tid;
        s_code[i] = unit >> 5;
        s_c8[i] = unit & 31;
    }

    // prefetch chunk 0 of the codebook into registers
    uint4 pre[8];
    #pragma unroll
    for (int i = 0; i < 8; ++i)
        pre[i] = *(const uint4*)(cb_h + (size_t)(0 * 64 + s_code[i]) * 256 + s_c8[i] * 8);

    // stage z tile (64 tok x 256 c bf16), layout [c8][tok] 16B units, XOR-swz
    for (int i = 0; i < 8; ++i) {
        int unit = i * 256 + tid;
        int tok = unit >> 5, c8 = unit & 31;
        uint4 v = *(const uint4*)(z_h + (size_t)(tok0 + tok) * 256 + c8 * 8);
        *(uint4*)(zs + c8 * 1024 + ((tok * 16) ^ ((c8 & 7) << 4))) = v;
    }
    if (tid < 64) cnt[tid] = 0;
    __syncthreads();

    // hoist A-fragments: afr[rt][cs]; lane holds z[rt*16+lr][cs*32+lq*8 ..+8]
    bf16x8 afr[4][8];
    #pragma unroll
    for (int rt = 0; rt < 4; ++rt)
        #pragma unroll
        for (int cs = 0; cs < 8; ++cs) {
            int tok = rt * 16 + lr;
            int c8 = cs * 4 + lq;
            afr[rt][cs] = *(const bf16x8*)(zs + c8 * 1024 + ((tok * 16) ^ ((c8 & 7) << 4)));
        }

    unsigned m1p[16], m2p[16];
    #pragma unroll
    for (int s = 0; s < 16; ++s) { m1p[s] = 0xFFFFFFFFu; m2p[s] = 0xFFFFFFFFu; }

    for (int kc = 0; kc < 16; ++kc) {
        __syncthreads();   // previous chunk's readers done with wsm
        // publish the prefetched chunk
        #pragma unroll
        for (int i = 0; i < 8; ++i)
            *(uint4*)(wsm + s_c8[i] * 1024 + ((s_code[i] * 16) ^ ((s_c8[i] & 7) << 4))) = pre[i];
        __syncthreads();   // wsm ready
        // issue next chunk's loads; latency hides under the MFMAs below
        if (kc < 15) {
            #pragma unroll
            for (int i = 0; i < 8; ++i)
                pre[i] = *(const uint4*)(cb_h + (size_t)((kc + 1) * 64 + s_code[i]) * 256 + s_c8[i] * 8);
        }
        const int kcode = kc * 64 + w * 16 + lr;   // this lane's code column
        const float bkv = Bk[kcode];
        f32x4 acc[4];
        #pragma unroll
        for (int rt = 0; rt < 4; ++rt) acc[rt] = (f32x4){0.f, 0.f, 0.f, 0.f};
        #pragma unroll
        for (int cs = 0; cs < 8; ++cs) {
            int c8 = cs * 4 + lq;
            int codeb = w * 16 + lr;
            bf16x8 bfr = *(const bf16x8*)(wsm + c8 * 1024 + ((codeb * 16) ^ ((c8 & 7) << 4)));
            #pragma unroll
            for (int rt = 0; rt < 4; ++rt)
                acc[rt] = __builtin_amdgcn_mfma_f32_16x16x32_bf16(afr[rt][cs], bfr, acc[rt], 0, 0, 0);
        }
        // packed top-2 update (est in Bk-2dot domain; |z|^2 cancels)
        #pragma unroll
        for (int s = 0; s < 16; ++s) {
            float est = fmaf(-2.0f, acc[s >> 2][s & 3], bkv);
            float x = fmaxf(est + 0.125f, 0.0f);
            unsigned q = (unsigned)(x * 8388608.0f);
            q = umin2(q, 2097151u);
            unsigned p = q * 1024u + (unsigned)kcode;
            if (p < m1p[s])      { m2p[s] = m1p[s]; m1p[s] = p; }
            else if (p < m2p[s]) { m2p[s] = p; }
        }
    }

    // per-token min of m1p over the 16 lr-lanes, then cross-wave via gpart
    #pragma unroll
    for (int s = 0; s < 16; ++s) {
        unsigned v = m1p[s];
        v = umin2(v, (unsigned)__shfl_xor((int)v, 1));
        v = umin2(v, (unsigned)__shfl_xor((int)v, 2));
        v = umin2(v, (unsigned)__shfl_xor((int)v, 4));
        v = umin2(v, (unsigned)__shfl_xor((int)v, 8));
        if (lr == 0) gpart[(s >> 2) * 16 + lq * 4 + (s & 3)][w] = v;
    }
    __syncthreads();

    // collect candidates from registers under the packed threshold
    {
        const int colid = w * 16 + lr;
        #pragma unroll
        for (int s = 0; s < 16; ++s) {
            int tl = (s >> 2) * 16 + lq * 4 + (s & 3);
            unsigned thrp = umin2(umin2(gpart[tl][0], gpart[tl][1]),
                                  umin2(gpart[tl][2], gpart[tl][3])) + MARGIN_P;
            if (m2p[s] <= thrp) {
                // >=2 band codes in this lane-slot: push the whole 16-code column
                int pos = atomicAdd(&cnt[tl], 16);
                #pragma unroll
                for (int kc = 0; kc < 16; ++kc)
                    if (pos + kc < NSLOT) ck[tl * NSLOT + pos + kc] = (unsigned short)(kc * 64 + colid);
            } else if (m1p[s] <= thrp) {
                int pos = atomicAdd(&cnt[tl], 1);
                if (pos < NSLOT) ck[tl * NSLOT + pos] = (unsigned short)(m1p[s] & 1023u);
            }
        }
    }
    __syncthreads();

    // exact rescore (bit-identical arithmetic), 4 threads per token
    {
        int tl = tid >> 2, ln = tid & 3;
        int total = cnt[tl];
        const float* zr = z_t + (size_t)(tok0 + tl) * 256;
        float Ag = A[tok0 + tl];
        float bd = 3.4e38f; int bki = 0x7fffffff;
        if (total <= NSLOT) {
            for (int s = ln; s < total; s += 4) {
                int k = ck[tl * NSLOT + s];
                const float* wr = cb + (size_t)k * 256;
                float acc = 0.0f;
                for (int c = 0; c < 256; c += 4) {
                    float4 zv = *(const float4*)&zr[c];
                    float4 wv = *(const float4*)&wr[c];
                    acc = fmaf(zv.x, wv.x, acc);
                    acc = fmaf(zv.y, wv.y, acc);
                    acc = fmaf(zv.z, wv.z, acc);
                    acc = fmaf(zv.w, wv.w, acc);
                }
                float d = fmaf(-2.0f, acc, Ag + Bk[k]);
                if (d < bd || (d == bd && k < bki)) { bd = d; bki = k; }
            }
        } else {
            // sound fallback (P ~ 1e-9): 4-way-split exact scan of all codes
            for (int k = ln; k < K_CODES; k += 4) {
                const float* wr = cb + (size_t)k * 256;
                float acc = 0.0f;
                for (int c = 0; c < 256; c += 4) {
                    float4 zv = *(const float4*)&zr[c];
                    float4 wv = *(const float4*)&wr[c];
                    acc = fmaf(zv.x, wv.x, acc);
                    acc = fmaf(zv.y, wv.y, acc);
                    acc = fmaf(zv.z, wv.z, acc);
                    acc = fmaf(zv.w, wv.w, acc);
                }
                float d = fmaf(-2.0f, acc, Ag + Bk[k]);
                if (d < bd || (d == bd && k < bki)) { bd = d; bki = k; }
            }
        }
        bval[tl][ln] = bd; bidx[tl][ln] = bki;
    }
    __syncthreads();
    if (tid < 64) {
        float bd = bval[tid][0]; int bki = bidx[tid][0];
        #pragma unroll
        for (int j = 1; j < 4; ++j) {
            float d = bval[tid][j]; int k = bidx[tid][j];
            if (d < bd || (d == bd && k < bki)) { bd = d; bki = k; }
        }
        out_idx[tok0 + tid] = (float)bki;
    }
}

// ---------------------------------------------------------------------------
// Output: out0 = z + (w - z) elementwise (NCHW), loss partials.
// ---------------------------------------------------------------------------
__global__ __launch_bounds__(256, 2) void out_kernel(const float* __restrict__ z,
        const float* __restrict__ cb, const float* __restrict__ out_idx_f,
        float* __restrict__ out0, double* __restrict__ lacc) {
#pragma clang fp contract(off)
    __shared__ float wl[64 * 257];
    __shared__ int fi[64];
    __shared__ double red[256];
    const int t = threadIdx.x, blk = blockIdx.x;
    const int b = blk >> 4, hw0 = (blk & 15) * 64;
    const size_t zb = (size_t)b * (C_DIM * HW) + hw0;
    if (t < 64) fi[t] = (int)out_idx_f[blk * 64 + t];
    __syncthreads();
    for (int i = 0; i < 64; ++i) {
        int pos = i * 256 + t;
        int row = pos >> 8, c = pos & 255;
        wl[row * 257 + c] = cb[(size_t)fi[row] * 256 + c];
    }
    __syncthreads();
    double lsum = 0.0;
    for (int i = 0; i < 64; ++i) {
        int pos = i * 256 + t;
        int c = pos >> 6, hw = pos & 63;
        float zv = z[zb + (size_t)c * HW + hw];
        float wv = wl[hw * 257 + c];
        float d = wv - zv;
        out0[zb + (size_t)c * HW + hw] = zv + d;
        float q = d * d;
        lsum += (double)q;
    }
    red[t] = lsum;
    __syncthreads();
    if (t == 0) {
        double s = 0.0;
        for (int i = 0; i < 256; ++i) s += red[i];
        atomicAdd(lacc, s);
    }
}

__global__ void loss_kernel(const double* __restrict__ acc, float* __restrict__ out_loss) {
    double mse = acc[0] / (double)OUT0_ELEMS;
    out_loss[0] = (float)(mse + 0.25 * mse);
}

extern "C" void kernel_launch(void* const* d_in, const int* in_sizes, int n_in,
                              void* d_out, int out_size, void* d_ws, size_t ws_size,
                              hipStream_t stream) {
    const float* z  = (const float*)d_in[0];
    const float* cb = (const float*)d_in[1];
    float* out      = (float*)d_out;
    float* out_idx  = out + OUT0_ELEMS;
    float* out_loss = out + OUT0_ELEMS + N_TOK;

    char* wsb = (char*)d_ws;
    double*         lacc = (double*)wsb;                       // 64 B
    float*          Bk   = (float*)(wsb + 64);                 // 4 KB
    float*          A    = (float*)(wsb + 8192);               // 128 KB
    unsigned short* cb_h = (unsigned short*)(wsb + 262144);    // 512 KB
    unsigned short* z_h  = (unsigned short*)(wsb + 1048576);   // 16 MB
    float*          z_t  = out;  // reuse out0 region as [N][C] f32 scratch

    hipMemsetAsync(d_ws, 0, 64, stream);
    zprep_kernel<<<512, 256, 0, stream>>>(z, z_t, z_h, A);
    cbh_bk_kernel<<<1024, 64, 0, stream>>>(cb, cb_h, Bk);
    vq_main<<<512, 256, 0, stream>>>(z_h, cb_h, A, Bk, z_t, cb, out_idx);
    out_kernel<<<512, 256, 0, stream>>>(z, cb, out_idx, out, lacc);
    loss_kernel<<<1, 1, 0, stream>>>(lacc, out_loss);
}

// Round 15
// 115.829 us; speedup vs baseline: 1.3722x; 1.3722x over previous
//
#include <hip/hip_runtime.h>

typedef __attribute__((ext_vector_type(8))) short bf16x8;
typedef __attribute__((ext_vector_type(4))) float f32x4;

#define C_DIM 256
#define K_CODES 1024
#define HW 1024
#define N_TOK 32768
#define OUT0_ELEMS 8388608
#define NSLOT 64
#define MARGIN_P (16777u * 1024u)   // 2e-3 * 2^23, in packed units

static __device__ __forceinline__ unsigned short f2bf(float f) {
    unsigned u = __float_as_uint(f);
    unsigned r = (u + 0x7FFFu + ((u >> 16) & 1u)) >> 16;
    return (unsigned short)r;
}
static __device__ __forceinline__ unsigned umin2(unsigned a, unsigned b) { return a < b ? a : b; }

// ---------------------------------------------------------------------------
// cb -> bf16 copy [K][C] + Bk (per-code |w|^2, numpy-pairwise f32, arithmetic
// bit-identical to the original bk_kernel, run by lane 0 of each block).
// ---------------------------------------------------------------------------
__global__ __launch_bounds__(64) void cbh_bk_kernel(const float* __restrict__ cb,
        unsigned short* __restrict__ cb_h, float* __restrict__ Bk) {
#pragma clang fp contract(off)
    int k = blockIdx.x, l = threadIdx.x;
    const float4 v = *(const float4*)&cb[k * C_DIM + l * 4];
    ushort4 o;
    o.x = f2bf(v.x); o.y = f2bf(v.y); o.z = f2bf(v.z); o.w = f2bf(v.w);
    *(ushort4*)&cb_h[k * C_DIM + l * 4] = o;
    if (l == 0) {
        const float* w = cb + k * C_DIM;
        float s[2];
        for (int h = 0; h < 2; ++h) {
            const float* p = w + h * 128;
            float r[8];
            #pragma unroll
            for (int j = 0; j < 8; ++j) { float vv = p[j]; r[j] = vv * vv; }
            for (int i = 8; i < 128; i += 8) {
                #pragma unroll
                for (int j = 0; j < 8; ++j) { float vv = p[i + j]; r[j] = r[j] + vv * vv; }
            }
            s[h] = ((r[0] + r[1]) + (r[2] + r[3])) + ((r[4] + r[5]) + (r[6] + r[7]));
        }
        Bk[k] = s[0] + s[1];
    }
}

// ---------------------------------------------------------------------------
// z prep: NCHW f32 -> z_t f32 [N][C] (in d_out region, overwritten later by
// out_kernel), z_h bf16 [N][C], A[N] = |z|^2 numpy-pairwise.
// ---------------------------------------------------------------------------
__global__ __launch_bounds__(256) void zprep_kernel(const float* __restrict__ z,
        float* __restrict__ z_t, unsigned short* __restrict__ z_h,
        float* __restrict__ A) {
#pragma clang fp contract(off)
    __shared__ float tile[64 * 257];
    const int t = threadIdx.x, blk = blockIdx.x;
    const int b = blk >> 4, hw0 = (blk & 15) * 64, tok0 = blk * 64;
    const size_t zb = (size_t)b * (C_DIM * HW) + hw0;
    for (int i = 0; i < 64; ++i) {
        int pos = i * 256 + t;
        int c = pos >> 6, hw = pos & 63;
        tile[hw * 257 + c] = z[zb + (size_t)c * HW + hw];
    }
    __syncthreads();
    if (t < 64) {
        const float* p0 = &tile[t * 257];
        float s[2];
        for (int h = 0; h < 2; ++h) {
            const float* p = p0 + h * 128;
            float r[8];
            #pragma unroll
            for (int j = 0; j < 8; ++j) { float v = p[j]; r[j] = v * v; }
            for (int i = 8; i < 128; i += 8) {
                #pragma unroll
                for (int j = 0; j < 8; ++j) { float v = p[i + j]; r[j] = r[j] + v * v; }
            }
            s[h] = ((r[0] + r[1]) + (r[2] + r[3])) + ((r[4] + r[5]) + (r[6] + r[7]));
        }
        A[tok0 + t] = s[0] + s[1];
    }
    for (int i = 0; i < 64; ++i) {
        int pos = i * 256 + t;
        int tl = pos >> 8, c = pos & 255;
        float v = tile[tl * 257 + c];
        z_t[(size_t)(tok0 + tl) * 256 + c] = v;
        z_h[(size_t)(tok0 + tl) * 256 + c] = f2bf(v);
    }
}

// ---------------------------------------------------------------------------
// Main: R13-exact proven structure. Staged wsm + afr hoist + packed top-2.
// ---------------------------------------------------------------------------
__global__ __launch_bounds__(256, 2) void vq_main(
        const unsigned short* __restrict__ z_h, const unsigned short* __restrict__ cb_h,
        const float* __restrict__ A, const float* __restrict__ Bk,
        const float* __restrict__ z_t, const float* __restrict__ cb,
        float* __restrict__ out_idx) {
#pragma clang fp contract(off)
    __shared__ __align__(16) char zs[32768];
    __shared__ __align__(16) char wsm[32768];
    __shared__ unsigned gpart[64][4];
    __shared__ int cnt[64];
    __shared__ unsigned short ck[64 * NSLOT];
    __shared__ float bval[64][4];
    __shared__ int   bidx[64][4];

    const int tid = threadIdx.x;
    const int w = tid >> 6, l = tid & 63;
    const int lq = l >> 4, lr = l & 15;
    const int tok0 = blockIdx.x * 64;

    // stage z tile (64 tok x 256 c bf16), layout [c8][tok] 16B units, XOR-swz
    for (int i = 0; i < 8; ++i) {
        int unit = i * 256 + tid;
        int tok = unit >> 5, c8 = unit & 31;
        uint4 v = *(const uint4*)(z_h + (size_t)(tok0 + tok) * 256 + c8 * 8);
        *(uint4*)(zs + c8 * 1024 + ((tok * 16) ^ ((c8 & 7) << 4))) = v;
    }
    if (tid < 64) cnt[tid] = 0;
    __syncthreads();

    // hoist A-fragments: afr[rt][cs]; lane holds z[rt*16+lr][cs*32+lq*8 ..+8]
    bf16x8 afr[4][8];
    #pragma unroll
    for (int rt = 0; rt < 4; ++rt)
        #pragma unroll
        for (int cs = 0; cs < 8; ++cs) {
            int tok = rt * 16 + lr;
            int c8 = cs * 4 + lq;
            afr[rt][cs] = *(const bf16x8*)(zs + c8 * 1024 + ((tok * 16) ^ ((c8 & 7) << 4)));
        }

    unsigned m1p[16], m2p[16];
    #pragma unroll
    for (int s = 0; s < 16; ++s) { m1p[s] = 0xFFFFFFFFu; m2p[s] = 0xFFFFFFFFu; }

    for (int kc = 0; kc < 16; ++kc) {
        __syncthreads();
        // stage 64-code chunk of bf16 codebook, same layout/swizzle
        for (int i = 0; i < 8; ++i) {
            int unit = i * 256 + tid;
            int code = unit >> 5, c8 = unit & 31;
            uint4 v = *(const uint4*)(cb_h + (size_t)(kc * 64 + code) * 256 + c8 * 8);
            *(uint4*)(wsm + c8 * 1024 + ((code * 16) ^ ((c8 & 7) << 4))) = v;
        }
        __syncthreads();
        const int kcode = kc * 64 + w * 16 + lr;   // this lane's code column
        const float bkv = Bk[kcode];
        f32x4 acc[4];
        #pragma unroll
        for (int rt = 0; rt < 4; ++rt) acc[rt] = (f32x4){0.f, 0.f, 0.f, 0.f};
        #pragma unroll
        for (int cs = 0; cs < 8; ++cs) {
            int c8 = cs * 4 + lq;
            int codeb = w * 16 + lr;
            bf16x8 bfr = *(const bf16x8*)(wsm + c8 * 1024 + ((codeb * 16) ^ ((c8 & 7) << 4)));
            #pragma unroll
            for (int rt = 0; rt < 4; ++rt)
                acc[rt] = __builtin_amdgcn_mfma_f32_16x16x32_bf16(afr[rt][cs], bfr, acc[rt], 0, 0, 0);
        }
        // packed top-2 update (est in Bk-2dot domain; |z|^2 cancels)
        #pragma unroll
        for (int s = 0; s < 16; ++s) {
            float est = fmaf(-2.0f, acc[s >> 2][s & 3], bkv);
            float x = fmaxf(est + 0.125f, 0.0f);
            unsigned q = (unsigned)(x * 8388608.0f);
            q = umin2(q, 2097151u);
            unsigned p = q * 1024u + (unsigned)kcode;
            if (p < m1p[s])      { m2p[s] = m1p[s]; m1p[s] = p; }
            else if (p < m2p[s]) { m2p[s] = p; }
        }
    }

    // per-token min of m1p over the 16 lr-lanes, then cross-wave via gpart
    #pragma unroll
    for (int s = 0; s < 16; ++s) {
        unsigned v = m1p[s];
        v = umin2(v, (unsigned)__shfl_xor((int)v, 1));
        v = umin2(v, (unsigned)__shfl_xor((int)v, 2));
        v = umin2(v, (unsigned)__shfl_xor((int)v, 4));
        v = umin2(v, (unsigned)__shfl_xor((int)v, 8));
        if (lr == 0) gpart[(s >> 2) * 16 + lq * 4 + (s & 3)][w] = v;
    }
    __syncthreads();

    // collect candidates from registers under the packed threshold
    {
        const int colid = w * 16 + lr;
        #pragma unroll
        for (int s = 0; s < 16; ++s) {
            int tl = (s >> 2) * 16 + lq * 4 + (s & 3);
            unsigned thrp = umin2(umin2(gpart[tl][0], gpart[tl][1]),
                                  umin2(gpart[tl][2], gpart[tl][3])) + MARGIN_P;
            if (m2p[s] <= thrp) {
                // >=2 band codes in this lane-slot: push the whole 16-code column
                int pos = atomicAdd(&cnt[tl], 16);
                #pragma unroll
                for (int kc = 0; kc < 16; ++kc)
                    if (pos + kc < NSLOT) ck[tl * NSLOT + pos + kc] = (unsigned short)(kc * 64 + colid);
            } else if (m1p[s] <= thrp) {
                int pos = atomicAdd(&cnt[tl], 1);
                if (pos < NSLOT) ck[tl * NSLOT + pos] = (unsigned short)(m1p[s] & 1023u);
            }
        }
    }
    __syncthreads();

    // exact rescore (bit-identical arithmetic), 4 threads per token
    {
        int tl = tid >> 2, ln = tid & 3;
        int total = cnt[tl];
        const float* zr = z_t + (size_t)(tok0 + tl) * 256;
        float Ag = A[tok0 + tl];
        float bd = 3.4e38f; int bki = 0x7fffffff;
        if (total <= NSLOT) {
            for (int s = ln; s < total; s += 4) {
                int k = ck[tl * NSLOT + s];
                const float* wr = cb + (size_t)k * 256;
                float acc = 0.0f;
                for (int c = 0; c < 256; c += 4) {
                    float4 zv = *(const float4*)&zr[c];
                    float4 wv = *(const float4*)&wr[c];
                    acc = fmaf(zv.x, wv.x, acc);
                    acc = fmaf(zv.y, wv.y, acc);
                    acc = fmaf(zv.z, wv.z, acc);
                    acc = fmaf(zv.w, wv.w, acc);
                }
                float d = fmaf(-2.0f, acc, Ag + Bk[k]);
                if (d < bd || (d == bd && k < bki)) { bd = d; bki = k; }
            }
        } else {
            // sound fallback (P ~ 1e-9): 4-way-split exact scan of all codes
            for (int k = ln; k < K_CODES; k += 4) {
                const float* wr = cb + (size_t)k * 256;
                float acc = 0.0f;
                for (int c = 0; c < 256; c += 4) {
                    float4 zv = *(const float4*)&zr[c];
                    float4 wv = *(const float4*)&wr[c];
                    acc = fmaf(zv.x, wv.x, acc);
                    acc = fmaf(zv.y, wv.y, acc);
                    acc = fmaf(zv.z, wv.z, acc);
                    acc = fmaf(zv.w, wv.w, acc);
                }
                float d = fmaf(-2.0f, acc, Ag + Bk[k]);
                if (d < bd || (d == bd && k < bki)) { bd = d; bki = k; }
            }
        }
        bval[tl][ln] = bd; bidx[tl][ln] = bki;
    }
    __syncthreads();
    if (tid < 64) {
        float bd = bval[tid][0]; int bki = bidx[tid][0];
        #pragma unroll
        for (int j = 1; j < 4; ++j) {
            float d = bval[tid][j]; int k = bidx[tid][j];
            if (d < bd || (d == bd && k < bki)) { bd = d; bki = k; }
        }
        out_idx[tok0 + tid] = (float)bki;
    }
}

// ---------------------------------------------------------------------------
// Output: out0 = z + (w - z) elementwise (NCHW), loss partials; the LAST
// block to finish also finalizes the loss (fused loss_kernel).
// ---------------------------------------------------------------------------
__global__ __launch_bounds__(256, 2) void out_kernel(const float* __restrict__ z,
        const float* __restrict__ cb, const float* __restrict__ out_idx_f,
        float* __restrict__ out0, double* __restrict__ lacc,
        unsigned* __restrict__ done_ctr, float* __restrict__ out_loss) {
#pragma clang fp contract(off)
    __shared__ float wl[64 * 257];
    __shared__ int fi[64];
    __shared__ double red[256];
    const int t = threadIdx.x, blk = blockIdx.x;
    const int b = blk >> 4, hw0 = (blk & 15) * 64;
    const size_t zb = (size_t)b * (C_DIM * HW) + hw0;
    if (t < 64) fi[t] = (int)out_idx_f[blk * 64 + t];
    __syncthreads();
    for (int i = 0; i < 64; ++i) {
        int pos = i * 256 + t;
        int row = pos >> 8, c = pos & 255;
        wl[row * 257 + c] = cb[(size_t)fi[row] * 256 + c];
    }
    __syncthreads();
    double lsum = 0.0;
    for (int i = 0; i < 64; ++i) {
        int pos = i * 256 + t;
        int c = pos >> 6, hw = pos & 63;
        float zv = z[zb + (size_t)c * HW + hw];
        float wv = wl[hw * 257 + c];
        float d = wv - zv;
        out0[zb + (size_t)c * HW + hw] = zv + d;
        float q = d * d;
        lsum += (double)q;
    }
    red[t] = lsum;
    __syncthreads();
    if (t == 0) {
        double s = 0.0;
        for (int i = 0; i < 256; ++i) s += red[i];
        atomicAdd(lacc, s);
        __threadfence();
        unsigned done = atomicAdd(done_ctr, 1u);
        if (done == gridDim.x - 1) {
            double tot = atomicAdd(lacc, 0.0);   // coherent read-back
            double mse = tot / (double)OUT0_ELEMS;
            out_loss[0] = (float)(mse + 0.25 * mse);
        }
    }
}

extern "C" void kernel_launch(void* const* d_in, const int* in_sizes, int n_in,
                              void* d_out, int out_size, void* d_ws, size_t ws_size,
                              hipStream_t stream) {
    const float* z  = (const float*)d_in[0];
    const float* cb = (const float*)d_in[1];
    float* out      = (float*)d_out;
    float* out_idx  = out + OUT0_ELEMS;
    float* out_loss = out + OUT0_ELEMS + N_TOK;

    char* wsb = (char*)d_ws;
    double*         lacc = (double*)wsb;                       // offset 0
    unsigned*       dctr = (unsigned*)(wsb + 8);               // offset 8
    float*          Bk   = (float*)(wsb + 64);                 // 4 KB
    float*          A    = (float*)(wsb + 8192);               // 128 KB
    unsigned short* cb_h = (unsigned short*)(wsb + 262144);    // 512 KB
    unsigned short* z_h  = (unsigned short*)(wsb + 1048576);   // 16 MB
    float*          z_t  = out;  // reuse out0 region as [N][C] f32 scratch

    hipMemsetAsync(d_ws, 0, 64, stream);
    cbh_bk_kernel<<<1024, 64, 0, stream>>>(cb, cb_h, Bk);
    zprep_kernel<<<512, 256, 0, stream>>>(z, z_t, z_h, A);
    vq_main<<<512, 256, 0, stream>>>(z_h, cb_h, A, Bk, z_t, cb, out_idx);
    out_kernel<<<512, 256, 0, stream>>>(z, cb, out_idx, out, lacc, dctr, out_loss);
}